// Round 1
// 934.177 us; speedup vs baseline: 1.4973x; 1.4973x over previous
//
#include <hip/hip_runtime.h>
#include <hip/hip_bf16.h>
#include <stdint.h>

// fp32 I/O. x[8,4096,1024]; Wq/Wk/Wv[1024,1024] (row = out feature); b*[1024].
// Channel-attention collapse:
//   G_b = X_b^T X_b (fp32, stored in d_out scratch), c = X^T 1, diag = sum x^2
//   Z_b = Wq G_b  (batched bf16 MFMA GEMM, exact fp32 diagonal in epilogue)
//   L = 0.125(Z_h Wk_h^T + bq uk^T + uq bk^T + 4096 bq bk^T); P = softmax_e
//   Wo[hd,:] = sum_e P[d,e] Wv[he,:]  (bf16, ws); bo = P bv
//   Out_b = X_b Wo_b^T + bo  (fp32 out, overwrites scratch region last)

#define B_   8
#define S_   4096
#define E_   1024
#define H_   16

typedef float floatx4 __attribute__((ext_vector_type(4)));
typedef short short8  __attribute__((ext_vector_type(8)));

#define MFMA(a,b,c) __builtin_amdgcn_mfma_f32_16x16x32_bf16((a),(b),(c),0,0,0)

static __device__ __forceinline__ unsigned short f2bf(float x){
    __hip_bfloat16 h = __float2bfloat16(x);
    return __builtin_bit_cast(unsigned short, h);
}
static __device__ __forceinline__ float bf2f(unsigned short u){
    unsigned int w = ((unsigned int)u) << 16;
    return __builtin_bit_cast(float, w);
}
static __device__ __forceinline__ short8 lds_load8(const unsigned short* p) {
    union { ushort4 u4[2]; short8 s8; } f;
    f.u4[0] = *(const ushort4*)(p);
    f.u4[1] = *(const ushort4*)(p + 4);
    return f.s8;
}
// Transposed buffers (stride 64 shorts, 8 chunks of 8): phys = chunk ^ f(row)
static __device__ __forceinline__ int swz(int chunk, int row){
    return chunk ^ ((row >> 3) & 7) ^ (row & 7);
}
// Row-major k-contiguous buffer, stride 128 shorts, 16 chunks XOR row&15.
static __device__ __forceinline__ int rk_idx(int row, int col){
    return row * 128 + (((col >> 3) ^ (row & 15)) << 3) + (col & 7);
}
// 128x32 staging buffers (As/Bs style), 4 chunks of 8 XOR'd by row
#define SWIZ(row, q) ((q) ^ (((row) >> 1) & 3))

// ---------------------------------------------------------------------------
// Partial sums: cpart[chunk][b][e] = sum_{s in chunk} x ; d2part = sum x^2
// ---------------------------------------------------------------------------
__global__ __launch_bounds__(256) void sums_kernel(
    const float* __restrict__ X, float* __restrict__ cpart, float* __restrict__ d2part)
{
    const int b = blockIdx.y, chunk = blockIdx.z;
    const int e = blockIdx.x * 256 + threadIdx.x;
    const float* p = X + ((size_t)b * S_ + chunk * 256) * E_ + e;
    float s1 = 0.f, s2 = 0.f;
#pragma unroll 8
    for (int i = 0; i < 256; ++i) {
        float v = p[(size_t)i * E_];
        s1 += v; s2 += v * v;
    }
    cpart [(chunk * B_ + b) * E_ + e] = s1;
    d2part[(chunk * B_ + b) * E_ + e] = s2;
}

__global__ __launch_bounds__(256) void reduce_kernel(
    const float* __restrict__ cpart, const float* __restrict__ d2part,
    float* __restrict__ c, float* __restrict__ gdiag)
{
    const int idx = blockIdx.x * 256 + threadIdx.x;   // b*1024+e, 8192 total
    const int b = idx >> 10, e = idx & 1023;
    float s1 = 0.f, s2 = 0.f;
#pragma unroll
    for (int p = 0; p < 16; ++p) {
        s1 += cpart [(p * B_ + b) * E_ + e];
        s2 += d2part[(p * B_ + b) * E_ + e];
    }
    c[idx] = s1; gdiag[idx] = s2;
}

// ---------------------------------------------------------------------------
// uq[b][j] = Wq[j,:]·c_b ; uk[b][j] = Wk[j,:]·c_b   (all fp32)
// ---------------------------------------------------------------------------
__global__ __launch_bounds__(256) void uqk_kernel(
    const float* __restrict__ Wq, const float* __restrict__ Wk,
    const float* __restrict__ c, float* __restrict__ uq, float* __restrict__ uk)
{
    const int b = blockIdx.y;
    const int j = blockIdx.x * 256 + threadIdx.x;
    const float* cb = c + b * E_;
    const float* q = Wq + (size_t)j * E_;
    const float* k = Wk + (size_t)j * E_;
    float sq = 0.f, sk = 0.f;
    for (int i = 0; i < E_; i += 4) {
        float4 vq = *(const float4*)(q + i);
        float4 vk = *(const float4*)(k + i);
        float4 cv = *(const float4*)(cb + i);
        sq += vq.x*cv.x + vq.y*cv.y + vq.z*cv.z + vq.w*cv.w;
        sk += vk.x*cv.x + vk.y*cv.y + vk.z*cv.z + vk.w*cv.w;
    }
    uq[b * E_ + j] = sq;
    uk[b * E_ + j] = sk;
}

// ---------------------------------------------------------------------------
// Gram: G_b = X_b^T X_b, fp32 out. 36 upper-tri 128x128 tile pairs x 8 batches.
// fp32 X -> bf16 transposed LDS staging ([e][s], swz); 16x16x32 MFMA.
// Straight write + scattered mirror write for off-diag tiles.
// ---------------------------------------------------------------------------
__global__ __launch_bounds__(256) void gram_kernel(
    const float* __restrict__ X, float* __restrict__ G)
{
    const int b = blockIdx.y;
    int u = blockIdx.x, mb = 0;
    while (u >= 8 - mb) { u -= 8 - mb; ++mb; }
    const int nb = mb + u;
    const int m0 = mb * 128, n0 = nb * 128;
    const bool diag = (mb == nb);
    const int t = threadIdx.x, lane = t & 63, w = t >> 6;
    const int l15 = lane & 15, quad = lane >> 4;
    const int mw = 64 * (w >> 1), nw = 64 * (w & 1);

    __shared__ __align__(16) unsigned short At[128 * 64];
    __shared__ __align__(16) unsigned short Bt[128 * 64];

    const floatx4 fz = {0.f, 0.f, 0.f, 0.f};
    floatx4 acc[4][4];
#pragma unroll
    for (int i = 0; i < 4; ++i)
#pragma unroll
        for (int j = 0; j < 4; ++j) acc[i][j] = fz;

    const float* Xb = X + (size_t)b * S_ * E_;

    for (int s0 = 0; s0 < S_; s0 += 64) {
        __syncthreads();
#pragma unroll
        for (int it = 0; it < 8; ++it) {
            const int l = t + 256 * it;        // 0..2047
            const int e4 = l & 31, sl = l >> 5; // e4: float4 col, sl: 0..63
            float4 va = *(const float4*)(Xb + (size_t)(s0 + sl) * E_ + m0 + e4 * 4);
            const float av[4] = {va.x, va.y, va.z, va.w};
#pragma unroll
            for (int j = 0; j < 4; ++j) {
                const int e = e4 * 4 + j;
                At[e * 64 + swz(sl >> 3, e) * 8 + (sl & 7)] = f2bf(av[j]);
            }
            if (!diag) {
                float4 vb = *(const float4*)(Xb + (size_t)(s0 + sl) * E_ + n0 + e4 * 4);
                const float bvv[4] = {vb.x, vb.y, vb.z, vb.w};
#pragma unroll
                for (int j = 0; j < 4; ++j) {
                    const int e = e4 * 4 + j;
                    Bt[e * 64 + swz(sl >> 3, e) * 8 + (sl & 7)] = f2bf(bvv[j]);
                }
            }
        }
        __syncthreads();
        const unsigned short* Bp = diag ? At : Bt;
#pragma unroll
        for (int ks = 0; ks < 2; ++ks) {
            const int q = ks * 4 + quad;
            short8 af[4], bfr[4];
#pragma unroll
            for (int i = 0; i < 4; ++i) {
                const int row = mw + 16 * i + l15;
                af[i] = lds_load8(&At[row * 64 + swz(q, row) * 8]);
            }
#pragma unroll
            for (int j = 0; j < 4; ++j) {
                const int row = nw + 16 * j + l15;
                bfr[j] = lds_load8(&Bp[row * 64 + swz(q, row) * 8]);
            }
#pragma unroll
            for (int i = 0; i < 4; ++i)
#pragma unroll
                for (int j = 0; j < 4; ++j)
                    acc[i][j] = MFMA(af[i], bfr[j], acc[i][j]);
        }
    }

    float* Gb = G + (size_t)b * E_ * E_;
#pragma unroll
    for (int jt = 0; jt < 4; ++jt)
#pragma unroll
        for (int i = 0; i < 4; ++i)
#pragma unroll
            for (int r = 0; r < 4; ++r) {
                const int row = mw + 16 * i + quad * 4 + r;
                const int col = nw + 16 * jt + l15;
                const float v = acc[i][jt][r];
                Gb[(size_t)(m0 + row) * E_ + n0 + col] = v;
                if (!diag) Gb[(size_t)(n0 + col) * E_ + m0 + row] = v;
            }
}

// ---------------------------------------------------------------------------
// Z_b = Wq * Ghat_b  (Ghat = G with zeroed diagonal), fp32 out with exact
// fp32 diagonal term added in epilogue: Z[m,n] += Wq[m,n]*gdiag[n].
// Uses G symmetry: Z[m,n] = sum_k Wq[m,k] * G[n,k]  (row loads of G).
// 128x128 tile, BK=32, grid (8 n-tiles, 8 m-tiles, 8 batches) = 512 blocks.
// ---------------------------------------------------------------------------
__global__ __launch_bounds__(256) void z_kernel(
    const float* __restrict__ G, const float* __restrict__ WqF,
    const float* __restrict__ gdiag, float* __restrict__ Z)
{
    const int b = blockIdx.z;
    const int n0 = blockIdx.x * 128;
    const int m0 = blockIdx.y * 128;
    const int t = threadIdx.x, lane = t & 63, w = t >> 6;
    const int l15 = lane & 15, quad = lane >> 4;
    const int mw = 64 * (w >> 1), nw = 64 * (w & 1);

    __shared__ __align__(16) unsigned short As[128 * 32];
    __shared__ __align__(16) unsigned short Bs[128 * 32];

    const float* Gb = G + (size_t)b * E_ * E_;
    const float* gd = gdiag + b * E_;
    float* Zb = Z + (size_t)b * E_ * E_;

    const floatx4 fz = {0.f, 0.f, 0.f, 0.f};
    floatx4 acc[4][4];
#pragma unroll
    for (int i = 0; i < 4; ++i)
#pragma unroll
        for (int j = 0; j < 4; ++j) acc[i][j] = fz;

    for (int k0 = 0; k0 < E_; k0 += 32) {
        __syncthreads();
#pragma unroll
        for (int it = 0; it < 4; ++it) {     // A: Wq 128x32 fp32 -> bf16
            const int l = t + 256 * it;      // 0..1023
            const int c4 = l & 7, row = l >> 3;
            float4 v = *(const float4*)(WqF + (size_t)(m0 + row) * E_ + k0 + c4 * 4);
            ushort4 o = { f2bf(v.x), f2bf(v.y), f2bf(v.z), f2bf(v.w) };
            *(ushort4*)&As[row * 32 + SWIZ(row, c4 >> 1) * 8 + (c4 & 1) * 4] = o;
        }
#pragma unroll
        for (int it = 0; it < 4; ++it) {     // B: G rows n0.., cols k0.., zero diag
            const int l = t + 256 * it;      // 0..1023
            const int c4 = l & 7, row = l >> 3;
            const int n = n0 + row;
            float4 v = *(const float4*)(Gb + (size_t)n * E_ + k0 + c4 * 4);
            float vv[4] = {v.x, v.y, v.z, v.w};
            const int dj = n - (k0 + c4 * 4);   // zero where global k == n
            if (dj >= 0 && dj < 4) vv[dj] = 0.f;
            ushort4 o = { f2bf(vv[0]), f2bf(vv[1]), f2bf(vv[2]), f2bf(vv[3]) };
            *(ushort4*)&Bs[row * 32 + SWIZ(row, c4 >> 1) * 8 + (c4 & 1) * 4] = o;
        }
        __syncthreads();
        short8 af[4], bfr[4];
#pragma unroll
        for (int i = 0; i < 4; ++i) {
            const int row = mw + 16 * i + l15;
            af[i] = lds_load8(&As[row * 32 + SWIZ(row, quad) * 8]);
        }
#pragma unroll
        for (int j = 0; j < 4; ++j) {
            const int row = nw + 16 * j + l15;
            bfr[j] = lds_load8(&Bs[row * 32 + SWIZ(row, quad) * 8]);
        }
#pragma unroll
        for (int i = 0; i < 4; ++i)
#pragma unroll
            for (int j = 0; j < 4; ++j)
                acc[i][j] = MFMA(af[i], bfr[j], acc[i][j]);
    }

#pragma unroll
    for (int jt = 0; jt < 4; ++jt) {
        const int n = n0 + nw + 16 * jt + l15;
        const float g = gd[n];
#pragma unroll
        for (int i = 0; i < 4; ++i)
#pragma unroll
            for (int r = 0; r < 4; ++r) {
                const int m = m0 + mw + 16 * i + quad * 4 + r;
                Zb[(size_t)m * E_ + n] = acc[i][jt][r] + WqF[(size_t)m * E_ + n] * g;
            }
    }
}

// ---------------------------------------------------------------------------
// Per (b,h): stage Z_h (fp32 -> hi/lo bf16) + Wk_h (hi/lo);
// L = 0.125(Z Wk^T + biases); P = softmax; Wo = P Wv (bf16 to ws); bo = P bv.
// smem: ZH@0 ZL@16K KH@32K KL@48K | then PB@0 WVT@16K
// ---------------------------------------------------------------------------
__global__ __launch_bounds__(256) void attn_kernel(
    const float* __restrict__ Z,
    const float* __restrict__ bqF,
    const float* __restrict__ WkF, const float* __restrict__ bkF,
    const float* __restrict__ WvF, const float* __restrict__ bvF,
    const float* __restrict__ uq, const float* __restrict__ uk,
    unsigned short* __restrict__ Wo, float* __restrict__ bo)
{
    const int bh = blockIdx.x, b = bh >> 4, h = bh & 15;
    const int t = threadIdx.x, lane = t & 63, w = t >> 6;
    const int l15 = lane & 15, quad = lane >> 4;

    __shared__ __align__(16) unsigned char smem[65536];
    unsigned short* ZH  = (unsigned short*)(smem);
    unsigned short* ZL  = (unsigned short*)(smem + 16384);
    unsigned short* KH  = (unsigned short*)(smem + 32768);
    unsigned short* KL  = (unsigned short*)(smem + 49152);
    unsigned short* PB  = (unsigned short*)(smem);           // 64 x 72
    unsigned short* WVT = (unsigned short*)(smem + 16384);   // 64 x 64 swz

    const float* Zh  = Z   + ((size_t)b * E_ + h * 64) * E_;
    const float* Wkh = WkF + (size_t)(h * 64) * E_;
    const float* Wvh = WvF + (size_t)(h * 64) * E_;

    const floatx4 fz = {0.f, 0.f, 0.f, 0.f};
    floatx4 lacc[4] = {fz, fz, fz, fz};

    for (int ic = 0; ic < 8; ++ic) {
        __syncthreads();
        // stage Z chunk hi/lo (64 rows x 128 cols fp32)
#pragma unroll
        for (int it = 0; it < 8; ++it) {
            const int l = t + 256 * it;        // 0..2047
            const int c4 = l & 31, row = l >> 5;
            float4 v = *(const float4*)(Zh + (size_t)row * E_ + ic * 128 + c4 * 4);
            const float vv[4] = {v.x, v.y, v.z, v.w};
            ushort4 ohi, olo;
#pragma unroll
            for (int j = 0; j < 4; ++j) {
                const unsigned short hi = f2bf(vv[j]);
                ((unsigned short*)&ohi)[j] = hi;
                ((unsigned short*)&olo)[j] = f2bf(vv[j] - bf2f(hi));
            }
            const int off = row * 128 + (((c4 >> 1) ^ (row & 15)) << 3) + (c4 & 1) * 4;
            *(ushort4*)&ZH[off] = ohi;
            *(ushort4*)&ZL[off] = olo;
        }
        // stage Wk chunk hi/lo
#pragma unroll
        for (int it = 0; it < 8; ++it) {
            const int l = t + 256 * it;
            const int c4 = l & 31, row = l >> 5;
            float4 v = *(const float4*)(Wkh + (size_t)row * E_ + ic * 128 + c4 * 4);
            const float vv[4] = {v.x, v.y, v.z, v.w};
            ushort4 ohi, olo;
#pragma unroll
            for (int j = 0; j < 4; ++j) {
                const unsigned short hi = f2bf(vv[j]);
                ((unsigned short*)&ohi)[j] = hi;
                ((unsigned short*)&olo)[j] = f2bf(vv[j] - bf2f(hi));
            }
            const int off = row * 128 + (((c4 >> 1) ^ (row & 15)) << 3) + (c4 & 1) * 4;
            *(ushort4*)&KH[off] = ohi;
            *(ushort4*)&KL[off] = olo;
        }
        __syncthreads();
        // L += (Zhi+Zlo)(Wkhi+Wklo)^T  (drop lo*lo)
#pragma unroll
        for (int ks = 0; ks < 4; ++ks) {
            const short8 ah = lds_load8(&ZH[rk_idx(16 * w + l15, ks * 32 + quad * 8)]);
            const short8 al = lds_load8(&ZL[rk_idx(16 * w + l15, ks * 32 + quad * 8)]);
#pragma unroll
            for (int jt = 0; jt < 4; ++jt) {
                const short8 bh_ = lds_load8(&KH[rk_idx(16 * jt + l15, ks * 32 + quad * 8)]);
                const short8 bl_ = lds_load8(&KL[rk_idx(16 * jt + l15, ks * 32 + quad * 8)]);
                lacc[jt] = MFMA(ah, bh_, lacc[jt]);
                lacc[jt] = MFMA(ah, bl_, lacc[jt]);
                lacc[jt] = MFMA(al, bh_, lacc[jt]);
            }
        }
    }

    // bias + scale + softmax. Row d = 16w+quad*4+r; col e = 16jt+l15.
    float ukv[4], bkv[4];
#pragma unroll
    for (int jt = 0; jt < 4; ++jt) {
        const int he = h * 64 + 16 * jt + l15;
        ukv[jt] = uk[b * E_ + he];
        bkv[jt] = bkF[he];
    }
    float L[4][4];
#pragma unroll
    for (int r = 0; r < 4; ++r) {
        const int hd = h * 64 + 16 * w + quad * 4 + r;
        const float uqr = uq[b * E_ + hd];
        const float bqr = bqF[hd];
#pragma unroll
        for (int jt = 0; jt < 4; ++jt)
            L[jt][r] = 0.125f * (lacc[jt][r] + bqr * ukv[jt] + bkv[jt] * uqr
                                 + 4096.f * bqr * bkv[jt]);
    }
#pragma unroll
    for (int r = 0; r < 4; ++r) {
        float m = fmaxf(fmaxf(L[0][r], L[1][r]), fmaxf(L[2][r], L[3][r]));
#pragma unroll
        for (int mask = 1; mask < 16; mask <<= 1) m = fmaxf(m, __shfl_xor(m, mask, 64));
        float s = 0.f;
#pragma unroll
        for (int jt = 0; jt < 4; ++jt) { L[jt][r] = __expf(L[jt][r] - m); s += L[jt][r]; }
#pragma unroll
        for (int mask = 1; mask < 16; mask <<= 1) s += __shfl_xor(s, mask, 64);
        const float inv = 1.f / s;
#pragma unroll
        for (int jt = 0; jt < 4; ++jt) L[jt][r] *= inv;
    }

    __syncthreads();   // all waves done with ZH region before PB overwrite
#pragma unroll
    for (int jt = 0; jt < 4; ++jt)
#pragma unroll
        for (int r = 0; r < 4; ++r)
            PB[(16 * w + quad * 4 + r) * 72 + 16 * jt + l15] = f2bf(L[jt][r]);
    __syncthreads();

    if (t < 64) {
        float s = 0.f;
        for (int e = 0; e < 64; ++e) s += bf2f(PB[t * 72 + e]) * bvF[h * 64 + e];
        bo[b * E_ + h * 64 + t] = s;
    }

    // Wo[hd, nc*64..] = sum_e P[d,e] Wv[he, nc*64..]
    unsigned short* Wob = Wo + (size_t)b * E_ * E_;
    for (int nc = 0; nc < 16; ++nc) {
        __syncthreads();
#pragma unroll
        for (int it = 0; it < 4; ++it) {     // WVT[n][e] transposed from Wv rows
            const int l = t + 256 * it;      // 0..1023
            const int n4 = l & 15, e = l >> 4;   // e 0..63
            float4 v = *(const float4*)(Wvh + (size_t)e * E_ + nc * 64 + n4 * 4);
            const float vv[4] = {v.x, v.y, v.z, v.w};
#pragma unroll
            for (int j = 0; j < 4; ++j) {
                const int n = n4 * 4 + j;
                WVT[n * 64 + swz(e >> 3, n) * 8 + (e & 7)] = f2bf(vv[j]);
            }
        }
        __syncthreads();
        floatx4 oacc[4] = {fz, fz, fz, fz};
#pragma unroll
        for (int ks = 0; ks < 2; ++ks) {
            const short8 a = lds_load8(&PB[(16 * w + l15) * 72 + ks * 32 + quad * 8]);
            const int q = ks * 4 + quad;
#pragma unroll
            for (int jt = 0; jt < 4; ++jt) {
                const int row = 16 * jt + l15;
                const short8 bb = lds_load8(&WVT[row * 64 + swz(q, row) * 8]);
                oacc[jt] = MFMA(a, bb, oacc[jt]);
            }
        }
#pragma unroll
        for (int jt = 0; jt < 4; ++jt)
#pragma unroll
            for (int r = 0; r < 4; ++r)
                Wob[(size_t)(h * 64 + 16 * w + quad * 4 + r) * E_ + nc * 64 + 16 * jt + l15]
                    = f2bf(oacc[jt][r]);
    }
}

// ---------------------------------------------------------------------------
// Out_b = X_b Wo_b^T + bo  (fp32 out). 128x128 tile, BK=32.
// ---------------------------------------------------------------------------
__global__ __launch_bounds__(256) void out_gemm_kernel(
    const float* __restrict__ X, const unsigned short* __restrict__ Wo,
    const float* __restrict__ bo, float* __restrict__ Out)
{
    const int b = blockIdx.z;
    const int n0 = blockIdx.x * 128;
    const int m0 = blockIdx.y * 128;
    const int t = threadIdx.x, lane = t & 63, w = t >> 6;
    const int l15 = lane & 15, quad = lane >> 4;
    const int mw = 64 * (w >> 1), nw = 64 * (w & 1);

    __shared__ __align__(16) unsigned short As[128 * 32];
    __shared__ __align__(16) unsigned short Bs[128 * 32];

    const float* Xb = X + (size_t)b * S_ * E_;
    const unsigned short* Wb = Wo + (size_t)b * E_ * E_;
    const float* bob = bo + b * E_;
    float* Ob = Out + (size_t)b * S_ * E_;

    const floatx4 fz = {0.f, 0.f, 0.f, 0.f};
    floatx4 acc[4][4];
#pragma unroll
    for (int i = 0; i < 4; ++i)
#pragma unroll
        for (int j = 0; j < 4; ++j) acc[i][j] = fz;

    for (int k0 = 0; k0 < E_; k0 += 32) {
        __syncthreads();
#pragma unroll
        for (int it = 0; it < 4; ++it) {     // A: 128x32 fp32 -> bf16
            const int l = t + 256 * it;      // 0..1023
            const int c4 = l & 7, row = l >> 3;
            float4 v = *(const float4*)(Xb + (size_t)(m0 + row) * E_ + k0 + c4 * 4);
            ushort4 o = { f2bf(v.x), f2bf(v.y), f2bf(v.z), f2bf(v.w) };
            *(ushort4*)&As[row * 32 + SWIZ(row, c4 >> 1) * 8 + (c4 & 1) * 4] = o;
        }
#pragma unroll
        for (int it = 0; it < 2; ++it) {     // B: 128x32 bf16 (16B chunks)
            const int l = t + 256 * it;      // 0..511
            const int ch = l & 3, row = l >> 2;
            uint4 v = *(const uint4*)(Wb + (size_t)(n0 + row) * E_ + k0 + ch * 8);
            *(uint4*)&Bs[row * 32 + SWIZ(row, ch) * 8] = v;
        }
        __syncthreads();
        short8 af[4], bfr[4];
#pragma unroll
        for (int i = 0; i < 4; ++i) {
            const int row = mw + 16 * i + l15;
            af[i] = lds_load8(&As[row * 32 + SWIZ(row, quad) * 8]);
        }
#pragma unroll
        for (int j = 0; j < 4; ++j) {
            const int row = nw + 16 * j + l15;
            bfr[j] = lds_load8(&Bs[row * 32 + SWIZ(row, quad) * 8]);
        }
#pragma unroll
        for (int i = 0; i < 4; ++i)
#pragma unroll
            for (int j = 0; j < 4; ++j)
                acc[i][j] = MFMA(af[i], bfr[j], acc[i][j]);
    }

#pragma unroll
    for (int jt = 0; jt < 4; ++jt) {
        const int n = n0 + nw + 16 * jt + l15;
        const float bv_ = bob[n];
        float* colp = Ob + n;
#pragma unroll
        for (int i = 0; i < 4; ++i)
#pragma unroll
            for (int r = 0; r < 4; ++r) {
                const int m = m0 + mw + 16 * i + quad * 4 + r;
                colp[(size_t)m * E_] = acc[i][jt][r] + bv_;
            }
    }
}

// ---------------------------------------------------------------------------
extern "C" void kernel_launch(void* const* d_in, const int* in_sizes, int n_in,
                              void* d_out, int out_size, void* d_ws, size_t ws_size,
                              hipStream_t stream) {
    (void)in_sizes; (void)n_in; (void)out_size; (void)ws_size;
    const float* x  = (const float*)d_in[0];
    const float* Wq = (const float*)d_in[1];
    const float* bq = (const float*)d_in[2];
    const float* Wk = (const float*)d_in[3];
    const float* bk = (const float*)d_in[4];
    const float* Wv = (const float*)d_in[5];
    const float* bv = (const float*)d_in[6];

    // ws: Wo bf16 (16 MiB) | cpart,d2part (1 MiB) | c,gdiag,uq,uk,bo (160 KiB)
    unsigned short* Wo = (unsigned short*)d_ws;
    float* cpart  = (float*)(Wo + (size_t)B_ * E_ * E_);
    float* d2part = cpart  + 16 * B_ * E_;
    float* c      = d2part + 16 * B_ * E_;
    float* gdiag  = c      + B_ * E_;
    float* uq     = gdiag  + B_ * E_;
    float* uk     = uq     + B_ * E_;
    float* bo     = uk     + B_ * E_;

    // Scratch inside d_out (128 MiB): G fp32 at [0,32MiB), Z fp32 at [32,64MiB).
    // out_gemm overwrites the whole buffer last.
    float* G = (float*)d_out;
    float* Z = (float*)((char*)d_out + ((size_t)32 << 20));

    sums_kernel<<<dim3(4, 8, 16), 256, 0, stream>>>(x, cpart, d2part);
    reduce_kernel<<<dim3(32), 256, 0, stream>>>(cpart, d2part, c, gdiag);
    uqk_kernel<<<dim3(4, 8), 256, 0, stream>>>(Wq, Wk, c, uq, uk);
    gram_kernel<<<dim3(36, 8), 256, 0, stream>>>(x, G);
    z_kernel<<<dim3(8, 8, 8), 256, 0, stream>>>(G, Wq, gdiag, Z);
    attn_kernel<<<dim3(128), 256, 0, stream>>>(Z, bq, Wk, bk, Wv, bv,
                                               uq, uk, Wo, bo);
    out_gemm_kernel<<<dim3(8, 32, 8), 256, 0, stream>>>(x, Wo, bo, (float*)d_out);
}

// Round 2
// 765.949 us; speedup vs baseline: 1.8262x; 1.2196x over previous
//
#include <hip/hip_runtime.h>
#include <hip/hip_bf16.h>
#include <stdint.h>

// fp32 I/O. x[8,4096,1024]; Wq/Wk/Wv[1024,1024] (row = out feature); b*[1024].
// Channel-attention collapse:
//   G_b = X_b^T X_b (fp32, K-split x4 partials in d_out, reduced in-place)
//   Z_b = Wq G_b  (batched bf16 MFMA GEMM, exact fp32 diagonal in epilogue)
//   L = 0.125(Z_h Wk_h^T + bq uk^T + uq bk^T + 4096 bq bk^T); P = softmax_e
//   Wo[hd,:] = sum_e P[d,e] Wv[he,:]  (bf16, ws); bo = P bv
//   Out_b = X_b Wo_b^T + bo  (fp32 out, overwrites scratch region last)

#define B_   8
#define S_   4096
#define E_   1024
#define H_   16
#define NSPLIT 4

typedef float floatx4 __attribute__((ext_vector_type(4)));
typedef short short8  __attribute__((ext_vector_type(8)));

#define MFMA(a,b,c) __builtin_amdgcn_mfma_f32_16x16x32_bf16((a),(b),(c),0,0,0)

static __device__ __forceinline__ unsigned short f2bf(float x){
    __hip_bfloat16 h = __float2bfloat16(x);
    return __builtin_bit_cast(unsigned short, h);
}
static __device__ __forceinline__ float bf2f(unsigned short u){
    unsigned int w = ((unsigned int)u) << 16;
    return __builtin_bit_cast(float, w);
}
static __device__ __forceinline__ short8 lds_load8(const unsigned short* p) {
    union { ushort4 u4[2]; short8 s8; } f;
    f.u4[0] = *(const ushort4*)(p);
    f.u4[1] = *(const ushort4*)(p + 4);
    return f.s8;
}
// Transposed buffers (stride 64 shorts, 8 chunks of 8): phys = chunk ^ f(row)
static __device__ __forceinline__ int swz(int chunk, int row){
    return chunk ^ ((row >> 3) & 7) ^ (row & 7);
}
// Row-major k-contiguous buffer, stride 128 shorts, 16 chunks XOR row&15.
static __device__ __forceinline__ int rk_idx(int row, int col){
    return row * 128 + (((col >> 3) ^ (row & 15)) << 3) + (col & 7);
}
// 128x32 staging buffers (As/Bs style), 4 chunks of 8 XOR'd by row
#define SWIZ(row, q) ((q) ^ (((row) >> 1) & 3))

// ---------------------------------------------------------------------------
// Partial sums: cpart[chunk][b][e] = sum_{s in chunk} x ; d2part = sum x^2
// ---------------------------------------------------------------------------
__global__ __launch_bounds__(256) void sums_kernel(
    const float* __restrict__ X, float* __restrict__ cpart, float* __restrict__ d2part)
{
    const int b = blockIdx.y, chunk = blockIdx.z;
    const int e = blockIdx.x * 256 + threadIdx.x;
    const float* p = X + ((size_t)b * S_ + chunk * 256) * E_ + e;
    float s1 = 0.f, s2 = 0.f;
#pragma unroll 8
    for (int i = 0; i < 256; ++i) {
        float v = p[(size_t)i * E_];
        s1 += v; s2 += v * v;
    }
    cpart [(chunk * B_ + b) * E_ + e] = s1;
    d2part[(chunk * B_ + b) * E_ + e] = s2;
}

__global__ __launch_bounds__(256) void reduce_kernel(
    const float* __restrict__ cpart, const float* __restrict__ d2part,
    float* __restrict__ c, float* __restrict__ gdiag)
{
    const int idx = blockIdx.x * 256 + threadIdx.x;   // b*1024+e, 8192 total
    const int b = idx >> 10, e = idx & 1023;
    float s1 = 0.f, s2 = 0.f;
#pragma unroll
    for (int p = 0; p < 16; ++p) {
        s1 += cpart [(p * B_ + b) * E_ + e];
        s2 += d2part[(p * B_ + b) * E_ + e];
    }
    c[idx] = s1; gdiag[idx] = s2;
}

// ---------------------------------------------------------------------------
// uq[b][j] = Wq[j,:]·c_b ; uk[b][j] = Wk[j,:]·c_b   (all fp32)
// ---------------------------------------------------------------------------
__global__ __launch_bounds__(256) void uqk_kernel(
    const float* __restrict__ Wq, const float* __restrict__ Wk,
    const float* __restrict__ c, float* __restrict__ uq, float* __restrict__ uk)
{
    const int b = blockIdx.y;
    const int j = blockIdx.x * 256 + threadIdx.x;
    const float* cb = c + b * E_;
    const float* q = Wq + (size_t)j * E_;
    const float* k = Wk + (size_t)j * E_;
    float sq = 0.f, sk = 0.f;
    for (int i = 0; i < E_; i += 4) {
        float4 vq = *(const float4*)(q + i);
        float4 vk = *(const float4*)(k + i);
        float4 cv = *(const float4*)(cb + i);
        sq += vq.x*cv.x + vq.y*cv.y + vq.z*cv.z + vq.w*cv.w;
        sk += vk.x*cv.x + vk.y*cv.y + vk.z*cv.z + vk.w*cv.w;
    }
    uq[b * E_ + j] = sq;
    uk[b * E_ + j] = sk;
}

// ---------------------------------------------------------------------------
// Gram partials: Gp[ks][b] = X_b[ks-chunk]^T X_b[ks-chunk], fp32.
// 36 upper-tri 128x128 tile pairs x 8 batches x 4 K-splits = 1152 blocks.
// Staging: thread owns an 8s x 4e block -> register transpose -> b64 LDS
// writes into swizzled [e][s] layout (reads unchanged). 16x16x32 MFMA.
// ---------------------------------------------------------------------------
__global__ __launch_bounds__(256, 4) void gram_kernel(
    const float* __restrict__ X, float* __restrict__ Gp)
{
    const int b = blockIdx.y;
    const int ks = blockIdx.z;
    int u = blockIdx.x, mb = 0;
    while (u >= 8 - mb) { u -= 8 - mb; ++mb; }
    const int nb = mb + u;
    const int m0 = mb * 128, n0 = nb * 128;
    const bool diag = (mb == nb);
    const int t = threadIdx.x, lane = t & 63, w = t >> 6;
    const int l15 = lane & 15, quad = lane >> 4;
    const int mw = 64 * (w >> 1), nw = 64 * (w & 1);
    const int e4 = t & 31, sgrp = t >> 5;   // staging roles: 4e x 8s block

    __shared__ __align__(16) unsigned short At[128 * 64];
    __shared__ __align__(16) unsigned short Bt[128 * 64];

    const floatx4 fz = {0.f, 0.f, 0.f, 0.f};
    floatx4 acc[4][4];
#pragma unroll
    for (int i = 0; i < 4; ++i)
#pragma unroll
        for (int j = 0; j < 4; ++j) acc[i][j] = fz;

    const float* Xb = X + (size_t)b * S_ * E_;
    const int s_begin = ks * (S_ / NSPLIT);
    const int s_end   = s_begin + (S_ / NSPLIT);

    for (int s0 = s_begin; s0 < s_end; s0 += 64) {
        __syncthreads();
#pragma unroll
        for (int p = 0; p < 2; ++p) {
            float4 va[4], vb[4];
#pragma unroll
            for (int i = 0; i < 4; ++i) {
                const int sl = 8 * sgrp + 4 * p + i;
                va[i] = *(const float4*)(Xb + (size_t)(s0 + sl) * E_ + m0 + e4 * 4);
                if (!diag)
                    vb[i] = *(const float4*)(Xb + (size_t)(s0 + sl) * E_ + n0 + e4 * 4);
            }
#pragma unroll
            for (int j = 0; j < 4; ++j) {
                const int e = e4 * 4 + j;
                ushort4 wa;
                wa.x = f2bf(((const float*)&va[0])[j]);
                wa.y = f2bf(((const float*)&va[1])[j]);
                wa.z = f2bf(((const float*)&va[2])[j]);
                wa.w = f2bf(((const float*)&va[3])[j]);
                *(ushort4*)&At[e * 64 + swz(sgrp, e) * 8 + 4 * p] = wa;
                if (!diag) {
                    ushort4 wb;
                    wb.x = f2bf(((const float*)&vb[0])[j]);
                    wb.y = f2bf(((const float*)&vb[1])[j]);
                    wb.z = f2bf(((const float*)&vb[2])[j]);
                    wb.w = f2bf(((const float*)&vb[3])[j]);
                    *(ushort4*)&Bt[e * 64 + swz(sgrp, e) * 8 + 4 * p] = wb;
                }
            }
        }
        __syncthreads();
        const unsigned short* Bp = diag ? At : Bt;
#pragma unroll
        for (int kk = 0; kk < 2; ++kk) {
            const int q = kk * 4 + quad;
            short8 af[4], bfr[4];
#pragma unroll
            for (int i = 0; i < 4; ++i) {
                const int row = mw + 16 * i + l15;
                af[i] = lds_load8(&At[row * 64 + swz(q, row) * 8]);
            }
#pragma unroll
            for (int j = 0; j < 4; ++j) {
                const int row = nw + 16 * j + l15;
                bfr[j] = lds_load8(&Bp[row * 64 + swz(q, row) * 8]);
            }
#pragma unroll
            for (int i = 0; i < 4; ++i)
#pragma unroll
                for (int j = 0; j < 4; ++j)
                    acc[i][j] = MFMA(af[i], bfr[j], acc[i][j]);
        }
    }

    float* Gb = Gp + ((size_t)ks * B_ + b) * E_ * E_;
#pragma unroll
    for (int jt = 0; jt < 4; ++jt)
#pragma unroll
        for (int i = 0; i < 4; ++i)
#pragma unroll
            for (int r = 0; r < 4; ++r) {
                const int row = mw + 16 * i + quad * 4 + r;
                const int col = nw + 16 * jt + l15;
                const float v = acc[i][jt][r];
                Gb[(size_t)(m0 + row) * E_ + n0 + col] = v;
                if (!diag) Gb[(size_t)(n0 + col) * E_ + m0 + row] = v;
            }
}

// ---------------------------------------------------------------------------
// G (slot 0) += slots 1..3, in place. 8M floats.
// ---------------------------------------------------------------------------
__global__ __launch_bounds__(256) void greduce_kernel(float* __restrict__ Gp)
{
    const size_t n = (size_t)B_ * E_ * E_;
    const size_t i = ((size_t)blockIdx.x * 256 + threadIdx.x) * 4;
    float4 v0 = *(const float4*)(Gp + i);
    float4 v1 = *(const float4*)(Gp + n + i);
    float4 v2 = *(const float4*)(Gp + 2 * n + i);
    float4 v3 = *(const float4*)(Gp + 3 * n + i);
    float4 r = { v0.x + v1.x + v2.x + v3.x,
                 v0.y + v1.y + v2.y + v3.y,
                 v0.z + v1.z + v2.z + v3.z,
                 v0.w + v1.w + v2.w + v3.w };
    *(float4*)(Gp + i) = r;
}

// ---------------------------------------------------------------------------
// Z_b = Wq * Ghat_b  (Ghat = G with zeroed diagonal), fp32 out with exact
// fp32 diagonal term added in epilogue: Z[m,n] += Wq[m,n]*gdiag[n].
// Uses G symmetry: Z[m,n] = sum_k Wq[m,k] * G[n,k]  (row loads of G).
// 128x128 tile, BK=32, grid (8 n-tiles, 8 m-tiles, 8 batches) = 512 blocks.
// ---------------------------------------------------------------------------
__global__ __launch_bounds__(256) void z_kernel(
    const float* __restrict__ G, const float* __restrict__ WqF,
    const float* __restrict__ gdiag, float* __restrict__ Z)
{
    const int b = blockIdx.z;
    const int n0 = blockIdx.x * 128;
    const int m0 = blockIdx.y * 128;
    const int t = threadIdx.x, lane = t & 63, w = t >> 6;
    const int l15 = lane & 15, quad = lane >> 4;
    const int mw = 64 * (w >> 1), nw = 64 * (w & 1);

    __shared__ __align__(16) unsigned short As[128 * 32];
    __shared__ __align__(16) unsigned short Bs[128 * 32];

    const float* Gb = G + (size_t)b * E_ * E_;
    const float* gd = gdiag + b * E_;
    float* Zb = Z + (size_t)b * E_ * E_;

    const floatx4 fz = {0.f, 0.f, 0.f, 0.f};
    floatx4 acc[4][4];
#pragma unroll
    for (int i = 0; i < 4; ++i)
#pragma unroll
        for (int j = 0; j < 4; ++j) acc[i][j] = fz;

    for (int k0 = 0; k0 < E_; k0 += 32) {
        __syncthreads();
#pragma unroll
        for (int it = 0; it < 4; ++it) {     // A: Wq 128x32 fp32 -> bf16
            const int l = t + 256 * it;      // 0..1023
            const int c4 = l & 7, row = l >> 3;
            float4 v = *(const float4*)(WqF + (size_t)(m0 + row) * E_ + k0 + c4 * 4);
            ushort4 o = { f2bf(v.x), f2bf(v.y), f2bf(v.z), f2bf(v.w) };
            *(ushort4*)&As[row * 32 + SWIZ(row, c4 >> 1) * 8 + (c4 & 1) * 4] = o;
        }
#pragma unroll
        for (int it = 0; it < 4; ++it) {     // B: G rows n0.., cols k0.., zero diag
            const int l = t + 256 * it;      // 0..1023
            const int c4 = l & 7, row = l >> 3;
            const int n = n0 + row;
            float4 v = *(const float4*)(Gb + (size_t)n * E_ + k0 + c4 * 4);
            float vv[4] = {v.x, v.y, v.z, v.w};
            const int dj = n - (k0 + c4 * 4);   // zero where global k == n
            if (dj >= 0 && dj < 4) vv[dj] = 0.f;
            ushort4 o = { f2bf(vv[0]), f2bf(vv[1]), f2bf(vv[2]), f2bf(vv[3]) };
            *(ushort4*)&Bs[row * 32 + SWIZ(row, c4 >> 1) * 8 + (c4 & 1) * 4] = o;
        }
        __syncthreads();
        short8 af[4], bfr[4];
#pragma unroll
        for (int i = 0; i < 4; ++i) {
            const int row = mw + 16 * i + l15;
            af[i] = lds_load8(&As[row * 32 + SWIZ(row, quad) * 8]);
        }
#pragma unroll
        for (int j = 0; j < 4; ++j) {
            const int row = nw + 16 * j + l15;
            bfr[j] = lds_load8(&Bs[row * 32 + SWIZ(row, quad) * 8]);
        }
#pragma unroll
        for (int i = 0; i < 4; ++i)
#pragma unroll
            for (int j = 0; j < 4; ++j)
                acc[i][j] = MFMA(af[i], bfr[j], acc[i][j]);
    }

#pragma unroll
    for (int jt = 0; jt < 4; ++jt) {
        const int n = n0 + nw + 16 * jt + l15;
        const float g = gd[n];
#pragma unroll
        for (int i = 0; i < 4; ++i)
#pragma unroll
            for (int r = 0; r < 4; ++r) {
                const int m = m0 + mw + 16 * i + quad * 4 + r;
                Zb[(size_t)m * E_ + n] = acc[i][jt][r] + WqF[(size_t)m * E_ + n] * g;
            }
    }
}

// ---------------------------------------------------------------------------
// Per (b,h): stage Z_h (fp32 -> hi/lo bf16) + Wk_h (hi/lo);
// L = 0.125(Z Wk^T + biases); P = softmax; Wo = P Wv (bf16 to ws); bo = P bv.
// smem: ZH@0 ZL@16K KH@32K KL@48K | then PB@0 WVT@16K
// ---------------------------------------------------------------------------
__global__ __launch_bounds__(256) void attn_kernel(
    const float* __restrict__ Z,
    const float* __restrict__ bqF,
    const float* __restrict__ WkF, const float* __restrict__ bkF,
    const float* __restrict__ WvF, const float* __restrict__ bvF,
    const float* __restrict__ uq, const float* __restrict__ uk,
    unsigned short* __restrict__ Wo, float* __restrict__ bo)
{
    const int bh = blockIdx.x, b = bh >> 4, h = bh & 15;
    const int t = threadIdx.x, lane = t & 63, w = t >> 6;
    const int l15 = lane & 15, quad = lane >> 4;

    __shared__ __align__(16) unsigned char smem[65536];
    unsigned short* ZH  = (unsigned short*)(smem);
    unsigned short* ZL  = (unsigned short*)(smem + 16384);
    unsigned short* KH  = (unsigned short*)(smem + 32768);
    unsigned short* KL  = (unsigned short*)(smem + 49152);
    unsigned short* PB  = (unsigned short*)(smem);           // 64 x 72
    unsigned short* WVT = (unsigned short*)(smem + 16384);   // 64 x 64 swz

    const float* Zh  = Z   + ((size_t)b * E_ + h * 64) * E_;
    const float* Wkh = WkF + (size_t)(h * 64) * E_;
    const float* Wvh = WvF + (size_t)(h * 64) * E_;

    const floatx4 fz = {0.f, 0.f, 0.f, 0.f};
    floatx4 lacc[4] = {fz, fz, fz, fz};

    for (int ic = 0; ic < 8; ++ic) {
        __syncthreads();
        // stage Z chunk hi/lo (64 rows x 128 cols fp32)
#pragma unroll
        for (int it = 0; it < 8; ++it) {
            const int l = t + 256 * it;        // 0..2047
            const int c4 = l & 31, row = l >> 5;
            float4 v = *(const float4*)(Zh + (size_t)row * E_ + ic * 128 + c4 * 4);
            const float vv[4] = {v.x, v.y, v.z, v.w};
            ushort4 ohi, olo;
#pragma unroll
            for (int j = 0; j < 4; ++j) {
                const unsigned short hi = f2bf(vv[j]);
                ((unsigned short*)&ohi)[j] = hi;
                ((unsigned short*)&olo)[j] = f2bf(vv[j] - bf2f(hi));
            }
            const int off = row * 128 + (((c4 >> 1) ^ (row & 15)) << 3) + (c4 & 1) * 4;
            *(ushort4*)&ZH[off] = ohi;
            *(ushort4*)&ZL[off] = olo;
        }
        // stage Wk chunk hi/lo
#pragma unroll
        for (int it = 0; it < 8; ++it) {
            const int l = t + 256 * it;
            const int c4 = l & 31, row = l >> 5;
            float4 v = *(const float4*)(Wkh + (size_t)row * E_ + ic * 128 + c4 * 4);
            const float vv[4] = {v.x, v.y, v.z, v.w};
            ushort4 ohi, olo;
#pragma unroll
            for (int j = 0; j < 4; ++j) {
                const unsigned short hi = f2bf(vv[j]);
                ((unsigned short*)&ohi)[j] = hi;
                ((unsigned short*)&olo)[j] = f2bf(vv[j] - bf2f(hi));
            }
            const int off = row * 128 + (((c4 >> 1) ^ (row & 15)) << 3) + (c4 & 1) * 4;
            *(ushort4*)&KH[off] = ohi;
            *(ushort4*)&KL[off] = olo;
        }
        __syncthreads();
        // L += (Zhi+Zlo)(Wkhi+Wklo)^T  (drop lo*lo)
#pragma unroll
        for (int ks = 0; ks < 4; ++ks) {
            const short8 ah = lds_load8(&ZH[rk_idx(16 * w + l15, ks * 32 + quad * 8)]);
            const short8 al = lds_load8(&ZL[rk_idx(16 * w + l15, ks * 32 + quad * 8)]);
#pragma unroll
            for (int jt = 0; jt < 4; ++jt) {
                const short8 bh_ = lds_load8(&KH[rk_idx(16 * jt + l15, ks * 32 + quad * 8)]);
                const short8 bl_ = lds_load8(&KL[rk_idx(16 * jt + l15, ks * 32 + quad * 8)]);
                lacc[jt] = MFMA(ah, bh_, lacc[jt]);
                lacc[jt] = MFMA(ah, bl_, lacc[jt]);
                lacc[jt] = MFMA(al, bh_, lacc[jt]);
            }
        }
    }

    // bias + scale + softmax. Row d = 16w+quad*4+r; col e = 16jt+l15.
    float ukv[4], bkv[4];
#pragma unroll
    for (int jt = 0; jt < 4; ++jt) {
        const int he = h * 64 + 16 * jt + l15;
        ukv[jt] = uk[b * E_ + he];
        bkv[jt] = bkF[he];
    }
    float L[4][4];
#pragma unroll
    for (int r = 0; r < 4; ++r) {
        const int hd = h * 64 + 16 * w + quad * 4 + r;
        const float uqr = uq[b * E_ + hd];
        const float bqr = bqF[hd];
#pragma unroll
        for (int jt = 0; jt < 4; ++jt)
            L[jt][r] = 0.125f * (lacc[jt][r] + bqr * ukv[jt] + bkv[jt] * uqr
                                 + 4096.f * bqr * bkv[jt]);
    }
#pragma unroll
    for (int r = 0; r < 4; ++r) {
        float m = fmaxf(fmaxf(L[0][r], L[1][r]), fmaxf(L[2][r], L[3][r]));
#pragma unroll
        for (int mask = 1; mask < 16; mask <<= 1) m = fmaxf(m, __shfl_xor(m, mask, 64));
        float s = 0.f;
#pragma unroll
        for (int jt = 0; jt < 4; ++jt) { L[jt][r] = __expf(L[jt][r] - m); s += L[jt][r]; }
#pragma unroll
        for (int mask = 1; mask < 16; mask <<= 1) s += __shfl_xor(s, mask, 64);
        const float inv = 1.f / s;
#pragma unroll
        for (int jt = 0; jt < 4; ++jt) L[jt][r] *= inv;
    }

    __syncthreads();   // all waves done with ZH region before PB overwrite
#pragma unroll
    for (int jt = 0; jt < 4; ++jt)
#pragma unroll
        for (int r = 0; r < 4; ++r)
            PB[(16 * w + quad * 4 + r) * 72 + 16 * jt + l15] = f2bf(L[jt][r]);
    __syncthreads();

    if (t < 64) {
        float s = 0.f;
        for (int e = 0; e < 64; ++e) s += bf2f(PB[t * 72 + e]) * bvF[h * 64 + e];
        bo[b * E_ + h * 64 + t] = s;
    }

    // Wo[hd, nc*64..] = sum_e P[d,e] Wv[he, nc*64..]
    unsigned short* Wob = Wo + (size_t)b * E_ * E_;
    for (int nc = 0; nc < 16; ++nc) {
        __syncthreads();
#pragma unroll
        for (int it = 0; it < 4; ++it) {     // WVT[n][e] transposed from Wv rows
            const int l = t + 256 * it;      // 0..1023
            const int n4 = l & 15, e = l >> 4;   // e 0..63
            float4 v = *(const float4*)(Wvh + (size_t)e * E_ + nc * 64 + n4 * 4);
            const float vv[4] = {v.x, v.y, v.z, v.w};
#pragma unroll
            for (int j = 0; j < 4; ++j) {
                const int n = n4 * 4 + j;
                WVT[n * 64 + swz(e >> 3, n) * 8 + (e & 7)] = f2bf(vv[j]);
            }
        }
        __syncthreads();
        floatx4 oacc[4] = {fz, fz, fz, fz};
#pragma unroll
        for (int ks = 0; ks < 2; ++ks) {
            const short8 a = lds_load8(&PB[(16 * w + l15) * 72 + ks * 32 + quad * 8]);
            const int q = ks * 4 + quad;
#pragma unroll
            for (int jt = 0; jt < 4; ++jt) {
                const int row = 16 * jt + l15;
                const short8 bb = lds_load8(&WVT[row * 64 + swz(q, row) * 8]);
                oacc[jt] = MFMA(a, bb, oacc[jt]);
            }
        }
#pragma unroll
        for (int jt = 0; jt < 4; ++jt)
#pragma unroll
            for (int r = 0; r < 4; ++r)
                Wob[(size_t)(h * 64 + 16 * w + quad * 4 + r) * E_ + nc * 64 + 16 * jt + l15]
                    = f2bf(oacc[jt][r]);
    }
}

// ---------------------------------------------------------------------------
// Out_b = X_b Wo_b^T + bo  (fp32 out). 128x128 tile, BK=32.
// ---------------------------------------------------------------------------
__global__ __launch_bounds__(256) void out_gemm_kernel(
    const float* __restrict__ X, const unsigned short* __restrict__ Wo,
    const float* __restrict__ bo, float* __restrict__ Out)
{
    const int b = blockIdx.z;
    const int n0 = blockIdx.x * 128;
    const int m0 = blockIdx.y * 128;
    const int t = threadIdx.x, lane = t & 63, w = t >> 6;
    const int l15 = lane & 15, quad = lane >> 4;
    const int mw = 64 * (w >> 1), nw = 64 * (w & 1);

    __shared__ __align__(16) unsigned short As[128 * 32];
    __shared__ __align__(16) unsigned short Bs[128 * 32];

    const float* Xb = X + (size_t)b * S_ * E_;
    const unsigned short* Wb = Wo + (size_t)b * E_ * E_;
    const float* bob = bo + b * E_;
    float* Ob = Out + (size_t)b * S_ * E_;

    const floatx4 fz = {0.f, 0.f, 0.f, 0.f};
    floatx4 acc[4][4];
#pragma unroll
    for (int i = 0; i < 4; ++i)
#pragma unroll
        for (int j = 0; j < 4; ++j) acc[i][j] = fz;

    for (int k0 = 0; k0 < E_; k0 += 32) {
        __syncthreads();
#pragma unroll
        for (int it = 0; it < 4; ++it) {     // A: 128x32 fp32 -> bf16
            const int l = t + 256 * it;      // 0..1023
            const int c4 = l & 7, row = l >> 3;
            float4 v = *(const float4*)(Xb + (size_t)(m0 + row) * E_ + k0 + c4 * 4);
            ushort4 o = { f2bf(v.x), f2bf(v.y), f2bf(v.z), f2bf(v.w) };
            *(ushort4*)&As[row * 32 + SWIZ(row, c4 >> 1) * 8 + (c4 & 1) * 4] = o;
        }
#pragma unroll
        for (int it = 0; it < 2; ++it) {     // B: 128x32 bf16 (16B chunks)
            const int l = t + 256 * it;      // 0..511
            const int ch = l & 3, row = l >> 2;
            uint4 v = *(const uint4*)(Wb + (size_t)(n0 + row) * E_ + k0 + ch * 8);
            *(uint4*)&Bs[row * 32 + SWIZ(row, ch) * 8] = v;
        }
        __syncthreads();
        short8 af[4], bfr[4];
#pragma unroll
        for (int i = 0; i < 4; ++i) {
            const int row = mw + 16 * i + l15;
            af[i] = lds_load8(&As[row * 32 + SWIZ(row, quad) * 8]);
        }
#pragma unroll
        for (int j = 0; j < 4; ++j) {
            const int row = nw + 16 * j + l15;
            bfr[j] = lds_load8(&Bs[row * 32 + SWIZ(row, quad) * 8]);
        }
#pragma unroll
        for (int i = 0; i < 4; ++i)
#pragma unroll
            for (int j = 0; j < 4; ++j)
                acc[i][j] = MFMA(af[i], bfr[j], acc[i][j]);
    }

#pragma unroll
    for (int jt = 0; jt < 4; ++jt) {
        const int n = n0 + nw + 16 * jt + l15;
        const float bv_ = bob[n];
        float* colp = Ob + n;
#pragma unroll
        for (int i = 0; i < 4; ++i)
#pragma unroll
            for (int r = 0; r < 4; ++r) {
                const int m = m0 + mw + 16 * i + quad * 4 + r;
                colp[(size_t)m * E_] = acc[i][jt][r] + bv_;
            }
    }
}

// ---------------------------------------------------------------------------
extern "C" void kernel_launch(void* const* d_in, const int* in_sizes, int n_in,
                              void* d_out, int out_size, void* d_ws, size_t ws_size,
                              hipStream_t stream) {
    (void)in_sizes; (void)n_in; (void)out_size; (void)ws_size;
    const float* x  = (const float*)d_in[0];
    const float* Wq = (const float*)d_in[1];
    const float* bq = (const float*)d_in[2];
    const float* Wk = (const float*)d_in[3];
    const float* bk = (const float*)d_in[4];
    const float* Wv = (const float*)d_in[5];
    const float* bv = (const float*)d_in[6];

    // ws: Wo bf16 (16 MiB) | cpart,d2part (1 MiB) | c,gdiag,uq,uk,bo (160 KiB)
    unsigned short* Wo = (unsigned short*)d_ws;
    float* cpart  = (float*)(Wo + (size_t)B_ * E_ * E_);
    float* d2part = cpart  + 16 * B_ * E_;
    float* c      = d2part + 16 * B_ * E_;
    float* gdiag  = c      + B_ * E_;
    float* uq     = gdiag  + B_ * E_;
    float* uk     = uq     + B_ * E_;
    float* bo     = uk     + B_ * E_;

    // Scratch inside d_out (128 MiB): 4 gram partial slots of 32 MiB fill it.
    // greduce sums into slot 0 (=G); Z then reuses slot 1's region.
    // out_gemm overwrites the whole buffer last.
    float* Gp = (float*)d_out;
    float* G  = Gp;                                   // slot 0 after reduce
    float* Z  = Gp + (size_t)B_ * E_ * E_;            // slot 1 region

    sums_kernel<<<dim3(4, 8, 16), 256, 0, stream>>>(x, cpart, d2part);
    reduce_kernel<<<dim3(32), 256, 0, stream>>>(cpart, d2part, c, gdiag);
    uqk_kernel<<<dim3(4, 8), 256, 0, stream>>>(Wq, Wk, c, uq, uk);
    gram_kernel<<<dim3(36, 8, NSPLIT), 256, 0, stream>>>(x, Gp);
    greduce_kernel<<<dim3(8192), 256, 0, stream>>>(Gp);
    z_kernel<<<dim3(8, 8, 8), 256, 0, stream>>>(G, Wq, gdiag, Z);
    attn_kernel<<<dim3(128), 256, 0, stream>>>(Z, bq, Wk, bk, Wv, bv,
                                               uq, uk, Wo, bo);
    out_gemm_kernel<<<dim3(8, 32, 8), 256, 0, stream>>>(x, Wo, bo, (float*)d_out);
}

// Round 3
// 654.270 us; speedup vs baseline: 2.1379x; 1.1707x over previous
//
#include <hip/hip_runtime.h>
#include <hip/hip_bf16.h>
#include <stdint.h>

// fp32 I/O. x[8,4096,1024]; Wq/Wk/Wv[1024,1024] (row = out feature); b*[1024].
// Channel-attention collapse:
//   G_b = X_b^T X_b (fp32, K-split x4 partials in d_out, reduced in-place)
//   Z_b = Wq G_b  (batched bf16 MFMA GEMM, exact fp32 diagonal in epilogue)
//   L = 0.125(Z_h Wk_h^T + bq uk^T + uq bk^T + 4096 bq bk^T); P = softmax_e
//   Wo[hd,:] = sum_e P[d,e] Wv[he,:]  (bf16, ws); bo = P bv
//   Out_b = X_b Wo_b^T + bo  (fp32 out, overwrites scratch region last)

#define B_   8
#define S_   4096
#define E_   1024
#define H_   16
#define NSPLIT 4

typedef float floatx4 __attribute__((ext_vector_type(4)));
typedef short short8  __attribute__((ext_vector_type(8)));

#define MFMA(a,b,c) __builtin_amdgcn_mfma_f32_16x16x32_bf16((a),(b),(c),0,0,0)

static __device__ __forceinline__ unsigned short f2bf(float x){
    __hip_bfloat16 h = __float2bfloat16(x);
    return __builtin_bit_cast(unsigned short, h);
}
static __device__ __forceinline__ float bf2f(unsigned short u){
    unsigned int w = ((unsigned int)u) << 16;
    return __builtin_bit_cast(float, w);
}
static __device__ __forceinline__ short8 lds_load8(const unsigned short* p) {
    union { ushort4 u4[2]; short8 s8; } f;
    f.u4[0] = *(const ushort4*)(p);
    f.u4[1] = *(const ushort4*)(p + 4);
    return f.s8;
}
// Transposed buffers (stride 64 shorts, 8 chunks of 8): phys = chunk ^ f(row)
static __device__ __forceinline__ int swz(int chunk, int row){
    return chunk ^ ((row >> 3) & 7) ^ (row & 7);
}
// Row-major k-contiguous buffer, stride 128 shorts, 16 chunks XOR row&15.
static __device__ __forceinline__ int rk_idx(int row, int col){
    return row * 128 + (((col >> 3) ^ (row & 15)) << 3) + (col & 7);
}
// 128x32 staging buffers (As/Bs style), 4 chunks of 8 XOR'd by row
#define SWIZ(row, q) ((q) ^ (((row) >> 1) & 3))
// gram 128x32 transposed buffers: chunk ^= (row>>2)&3 (spreads writes 4-wide)
#define GSWZ(row, q) ((q) ^ (((row) >> 2) & 3))

// ---------------------------------------------------------------------------
// Partial sums: cpart[chunk][b][e] = sum_{s in chunk} x ; d2part = sum x^2
// ---------------------------------------------------------------------------
__global__ __launch_bounds__(256) void sums_kernel(
    const float* __restrict__ X, float* __restrict__ cpart, float* __restrict__ d2part)
{
    const int b = blockIdx.y, chunk = blockIdx.z;
    const int e = blockIdx.x * 256 + threadIdx.x;
    const float* p = X + ((size_t)b * S_ + chunk * 256) * E_ + e;
    float s1 = 0.f, s2 = 0.f;
#pragma unroll 8
    for (int i = 0; i < 256; ++i) {
        float v = p[(size_t)i * E_];
        s1 += v; s2 += v * v;
    }
    cpart [(chunk * B_ + b) * E_ + e] = s1;
    d2part[(chunk * B_ + b) * E_ + e] = s2;
}

__global__ __launch_bounds__(256) void reduce_kernel(
    const float* __restrict__ cpart, const float* __restrict__ d2part,
    float* __restrict__ c, float* __restrict__ gdiag)
{
    const int idx = blockIdx.x * 256 + threadIdx.x;   // b*1024+e, 8192 total
    const int b = idx >> 10, e = idx & 1023;
    float s1 = 0.f, s2 = 0.f;
#pragma unroll
    for (int p = 0; p < 16; ++p) {
        s1 += cpart [(p * B_ + b) * E_ + e];
        s2 += d2part[(p * B_ + b) * E_ + e];
    }
    c[idx] = s1; gdiag[idx] = s2;
}

// ---------------------------------------------------------------------------
// uq[b][j] = Wq[j,:]·c_b ; uk[b][j] = Wk[j,:]·c_b   (all fp32)
// ---------------------------------------------------------------------------
__global__ __launch_bounds__(256) void uqk_kernel(
    const float* __restrict__ Wq, const float* __restrict__ Wk,
    const float* __restrict__ c, float* __restrict__ uq, float* __restrict__ uk)
{
    const int b = blockIdx.y;
    const int j = blockIdx.x * 256 + threadIdx.x;
    const float* cb = c + b * E_;
    const float* q = Wq + (size_t)j * E_;
    const float* k = Wk + (size_t)j * E_;
    float sq = 0.f, sk = 0.f;
    for (int i = 0; i < E_; i += 4) {
        float4 vq = *(const float4*)(q + i);
        float4 vk = *(const float4*)(k + i);
        float4 cv = *(const float4*)(cb + i);
        sq += vq.x*cv.x + vq.y*cv.y + vq.z*cv.z + vq.w*cv.w;
        sk += vk.x*cv.x + vk.y*cv.y + vk.z*cv.z + vk.w*cv.w;
    }
    uq[b * E_ + j] = sq;
    uk[b * E_ + j] = sk;
}

// ---------------------------------------------------------------------------
// Gram partials: Gp[ks][b] = X_b[ks-chunk]^T X_b[ks-chunk], fp32.
// Flat grid 1152, decoded so XCD (bid%8) == batch: each XCD streams 16 MiB.
// K-step 32, double LDS buffer, register prefetch, 1 barrier/step.
// Thread stages a 4s x 4e block: coalesced loads, register transpose,
// b64 LDS writes into GSWZ layout; 16x16x32 MFMA.
// ---------------------------------------------------------------------------
__global__ __launch_bounds__(256, 3) void gram_kernel(
    const float* __restrict__ X, float* __restrict__ Gp)
{
    const int bid = blockIdx.x;
    const int v = (bid & 7) * 144 + (bid >> 3);   // XCD-grouped virtual id
    const int g = v / 36;                          // 0..31 = (b, ks)
    int u = v - g * 36;
    const int b = g >> 2, ks = g & 3;
    int mb = 0;
    while (u >= 8 - mb) { u -= 8 - mb; ++mb; }
    const int nb = mb + u;
    const int m0 = mb * 128, n0 = nb * 128;
    const bool diag = (mb == nb);
    const int t = threadIdx.x, lane = t & 63, w = t >> 6;
    const int l15 = lane & 15, quad = lane >> 4;
    const int mw = 64 * (w >> 1), nw = 64 * (w & 1);
    const int e4 = t & 31, sg = t >> 5;   // staging: cols 4*e4.., rows 4*sg..

    __shared__ __align__(16) unsigned short At[2][128 * 32];
    __shared__ __align__(16) unsigned short Bt[2][128 * 32];

    const floatx4 fz = {0.f, 0.f, 0.f, 0.f};
    floatx4 acc[4][4];
#pragma unroll
    for (int i = 0; i < 4; ++i)
#pragma unroll
        for (int j = 0; j < 4; ++j) acc[i][j] = fz;

    const float* Xb = X + (size_t)b * S_ * E_;
    const int s_begin = ks * (S_ / NSPLIT);
    const int s_end   = s_begin + (S_ / NSPLIT);

    float4 pa[4], pb[4];
    auto gload = [&](int s0) {
#pragma unroll
        for (int i = 0; i < 4; ++i) {
            const float* rp = Xb + (size_t)(s0 + 4 * sg + i) * E_;
            pa[i] = *(const float4*)(rp + m0 + e4 * 4);
            if (!diag) pb[i] = *(const float4*)(rp + n0 + e4 * 4);
        }
    };

    gload(s_begin);
    int cur = 0;
    for (int s0 = s_begin; s0 < s_end; s0 += 32) {
        // write held regs -> LDS[cur] (transpose in registers)
#pragma unroll
        for (int j = 0; j < 4; ++j) {
            const int e = e4 * 4 + j;
            const int off = e * 32 + (GSWZ(e, sg >> 1) << 3) + (sg & 1) * 4;
            ushort4 wa = { f2bf(((const float*)&pa[0])[j]), f2bf(((const float*)&pa[1])[j]),
                           f2bf(((const float*)&pa[2])[j]), f2bf(((const float*)&pa[3])[j]) };
            *(ushort4*)&At[cur][off] = wa;
            if (!diag) {
                ushort4 wb = { f2bf(((const float*)&pb[0])[j]), f2bf(((const float*)&pb[1])[j]),
                               f2bf(((const float*)&pb[2])[j]), f2bf(((const float*)&pb[3])[j]) };
                *(ushort4*)&Bt[cur][off] = wb;
            }
        }
        if (s0 + 32 < s_end) gload(s0 + 32);   // in flight across barrier+MFMA
        __syncthreads();
        const unsigned short* Ap = At[cur];
        const unsigned short* Bq = diag ? At[cur] : Bt[cur];
        short8 af[4], bfr[4];
#pragma unroll
        for (int i = 0; i < 4; ++i) {
            const int row = mw + 16 * i + l15;
            af[i] = lds_load8(&Ap[row * 32 + (GSWZ(row, quad) << 3)]);
        }
#pragma unroll
        for (int j = 0; j < 4; ++j) {
            const int row = nw + 16 * j + l15;
            bfr[j] = lds_load8(&Bq[row * 32 + (GSWZ(row, quad) << 3)]);
        }
#pragma unroll
        for (int i = 0; i < 4; ++i)
#pragma unroll
            for (int j = 0; j < 4; ++j)
                acc[i][j] = MFMA(af[i], bfr[j], acc[i][j]);
        cur ^= 1;
    }

    float* Gb = Gp + ((size_t)ks * B_ + b) * E_ * E_;
#pragma unroll
    for (int jt = 0; jt < 4; ++jt)
#pragma unroll
        for (int i = 0; i < 4; ++i)
#pragma unroll
            for (int r = 0; r < 4; ++r) {
                const int row = mw + 16 * i + quad * 4 + r;
                const int col = nw + 16 * jt + l15;
                const float v2 = acc[i][jt][r];
                Gb[(size_t)(m0 + row) * E_ + n0 + col] = v2;
                if (!diag) Gb[(size_t)(n0 + col) * E_ + m0 + row] = v2;
            }
}

// ---------------------------------------------------------------------------
// G (slot 0) += slots 1..3, in place. 8M floats.
// ---------------------------------------------------------------------------
__global__ __launch_bounds__(256) void greduce_kernel(float* __restrict__ Gp)
{
    const size_t n = (size_t)B_ * E_ * E_;
    const size_t i = ((size_t)blockIdx.x * 256 + threadIdx.x) * 4;
    float4 v0 = *(const float4*)(Gp + i);
    float4 v1 = *(const float4*)(Gp + n + i);
    float4 v2 = *(const float4*)(Gp + 2 * n + i);
    float4 v3 = *(const float4*)(Gp + 3 * n + i);
    float4 r = { v0.x + v1.x + v2.x + v3.x,
                 v0.y + v1.y + v2.y + v3.y,
                 v0.z + v1.z + v2.z + v3.z,
                 v0.w + v1.w + v2.w + v3.w };
    *(float4*)(Gp + i) = r;
}

// ---------------------------------------------------------------------------
// Z_b = Wq * Ghat_b  (Ghat = G with zeroed diagonal), fp32 out with exact
// fp32 diagonal term added in epilogue: Z[m,n] += Wq[m,n]*gdiag[n].
// Uses G symmetry: Z[m,n] = sum_k Wq[m,k] * G[n,k]  (row loads of G).
// Flat grid 512, XCD (bid%8) == batch (G_b + Wq stay L2-resident).
// Register prefetch: next K-chunk's loads issued before the MFMA phase.
// ---------------------------------------------------------------------------
__global__ __launch_bounds__(256) void z_kernel(
    const float* __restrict__ G, const float* __restrict__ WqF,
    const float* __restrict__ gdiag, float* __restrict__ Z)
{
    const int bid = blockIdx.x;
    const int b = bid & 7;
    const int rem = bid >> 3;           // 0..63
    const int n0 = (rem & 7) * 128;
    const int m0 = (rem >> 3) * 128;
    const int t = threadIdx.x, lane = t & 63, w = t >> 6;
    const int l15 = lane & 15, quad = lane >> 4;
    const int mw = 64 * (w >> 1), nw = 64 * (w & 1);
    const int c4 = t & 7, srow = t >> 3;    // staging roles

    __shared__ __align__(16) unsigned short As[128 * 32];
    __shared__ __align__(16) unsigned short Bs[128 * 32];

    const float* Gb = G + (size_t)b * E_ * E_;
    const float* gd = gdiag + b * E_;
    float* Zb = Z + (size_t)b * E_ * E_;

    const floatx4 fz = {0.f, 0.f, 0.f, 0.f};
    floatx4 acc[4][4];
#pragma unroll
    for (int i = 0; i < 4; ++i)
#pragma unroll
        for (int j = 0; j < 4; ++j) acc[i][j] = fz;

    float4 qa[4], gb4[4];
    auto zload = [&](int k0) {
#pragma unroll
        for (int it = 0; it < 4; ++it) {
            const int row = srow + 32 * it;     // interleave rows by it
            qa[it]  = *(const float4*)(WqF + (size_t)(m0 + row) * E_ + k0 + c4 * 4);
            gb4[it] = *(const float4*)(Gb  + (size_t)(n0 + row) * E_ + k0 + c4 * 4);
        }
    };

    zload(0);
    for (int k0 = 0; k0 < E_; k0 += 32) {
        __syncthreads();   // consumers of previous tile done
#pragma unroll
        for (int it = 0; it < 4; ++it) {
            const int row = srow + 32 * it;
            const int off = row * 32 + SWIZ(row, c4 >> 1) * 8 + (c4 & 1) * 4;
            ushort4 oa = { f2bf(qa[it].x), f2bf(qa[it].y), f2bf(qa[it].z), f2bf(qa[it].w) };
            *(ushort4*)&As[off] = oa;
            const int n = n0 + row;
            float vv[4] = {gb4[it].x, gb4[it].y, gb4[it].z, gb4[it].w};
            const int dj = n - (k0 + c4 * 4);   // zero where global k == n
            if (dj >= 0 && dj < 4) vv[dj] = 0.f;
            ushort4 ob = { f2bf(vv[0]), f2bf(vv[1]), f2bf(vv[2]), f2bf(vv[3]) };
            *(ushort4*)&Bs[off] = ob;
        }
        if (k0 + 32 < E_) zload(k0 + 32);
        __syncthreads();
        short8 af[4], bfr[4];
#pragma unroll
        for (int i = 0; i < 4; ++i) {
            const int row = mw + 16 * i + l15;
            af[i] = lds_load8(&As[row * 32 + SWIZ(row, quad) * 8]);
        }
#pragma unroll
        for (int j = 0; j < 4; ++j) {
            const int row = nw + 16 * j + l15;
            bfr[j] = lds_load8(&Bs[row * 32 + SWIZ(row, quad) * 8]);
        }
#pragma unroll
        for (int i = 0; i < 4; ++i)
#pragma unroll
            for (int j = 0; j < 4; ++j)
                acc[i][j] = MFMA(af[i], bfr[j], acc[i][j]);
    }

#pragma unroll
    for (int jt = 0; jt < 4; ++jt) {
        const int n = n0 + nw + 16 * jt + l15;
        const float gdi = gd[n];
#pragma unroll
        for (int i = 0; i < 4; ++i)
#pragma unroll
            for (int r = 0; r < 4; ++r) {
                const int m = m0 + mw + 16 * i + quad * 4 + r;
                Zb[(size_t)m * E_ + n] = acc[i][jt][r] + WqF[(size_t)m * E_ + n] * gdi;
            }
    }
}

// ---------------------------------------------------------------------------
// Per (b,h): stage Z_h (fp32 -> hi/lo bf16) + Wk_h (hi/lo);
// L = 0.125(Z Wk^T + biases); P = softmax; Wo = P Wv (bf16 to ws); bo = P bv.
// Register prefetch of next ic chunk overlaps the MFMA phase.
// smem: ZH@0 ZL@16K KH@32K KL@48K | then PB@0 WVT@16K
// ---------------------------------------------------------------------------
__global__ __launch_bounds__(256) void attn_kernel(
    const float* __restrict__ Z,
    const float* __restrict__ bqF,
    const float* __restrict__ WkF, const float* __restrict__ bkF,
    const float* __restrict__ WvF, const float* __restrict__ bvF,
    const float* __restrict__ uq, const float* __restrict__ uk,
    unsigned short* __restrict__ Wo, float* __restrict__ bo)
{
    const int bh = blockIdx.x, b = bh >> 4, h = bh & 15;
    const int t = threadIdx.x, lane = t & 63, w = t >> 6;
    const int l15 = lane & 15, quad = lane >> 4;

    __shared__ __align__(16) unsigned char smem[65536];
    unsigned short* ZH  = (unsigned short*)(smem);
    unsigned short* ZL  = (unsigned short*)(smem + 16384);
    unsigned short* KH  = (unsigned short*)(smem + 32768);
    unsigned short* KL  = (unsigned short*)(smem + 49152);
    unsigned short* PB  = (unsigned short*)(smem);           // 64 x 72
    unsigned short* WVT = (unsigned short*)(smem + 16384);   // 64 x 64 swz

    const float* Zh  = Z   + ((size_t)b * E_ + h * 64) * E_;
    const float* Wkh = WkF + (size_t)(h * 64) * E_;
    const float* Wvh = WvF + (size_t)(h * 64) * E_;

    const floatx4 fz = {0.f, 0.f, 0.f, 0.f};
    floatx4 lacc[4] = {fz, fz, fz, fz};

    float4 zv[8], kv[8];
    auto aload = [&](int ic) {
#pragma unroll
        for (int it = 0; it < 8; ++it) {
            const int l = t + 256 * it;
            const int cc = l & 31, row = l >> 5;
            zv[it] = *(const float4*)(Zh  + (size_t)row * E_ + ic * 128 + cc * 4);
            kv[it] = *(const float4*)(Wkh + (size_t)row * E_ + ic * 128 + cc * 4);
        }
    };

    aload(0);
    for (int ic = 0; ic < 8; ++ic) {
        __syncthreads();   // previous MFMA phase done with LDS
#pragma unroll
        for (int it = 0; it < 8; ++it) {
            const int l = t + 256 * it;
            const int cc = l & 31, row = l >> 5;
            const int off = row * 128 + (((cc >> 1) ^ (row & 15)) << 3) + (cc & 1) * 4;
            {
                const float vv[4] = {zv[it].x, zv[it].y, zv[it].z, zv[it].w};
                ushort4 ohi, olo;
#pragma unroll
                for (int j = 0; j < 4; ++j) {
                    const unsigned short hi = f2bf(vv[j]);
                    ((unsigned short*)&ohi)[j] = hi;
                    ((unsigned short*)&olo)[j] = f2bf(vv[j] - bf2f(hi));
                }
                *(ushort4*)&ZH[off] = ohi;
                *(ushort4*)&ZL[off] = olo;
            }
            {
                const float vv[4] = {kv[it].x, kv[it].y, kv[it].z, kv[it].w};
                ushort4 ohi, olo;
#pragma unroll
                for (int j = 0; j < 4; ++j) {
                    const unsigned short hi = f2bf(vv[j]);
                    ((unsigned short*)&ohi)[j] = hi;
                    ((unsigned short*)&olo)[j] = f2bf(vv[j] - bf2f(hi));
                }
                *(ushort4*)&KH[off] = ohi;
                *(ushort4*)&KL[off] = olo;
            }
        }
        if (ic < 7) aload(ic + 1);   // overlaps MFMA phase
        __syncthreads();
        // L += (Zhi+Zlo)(Wkhi+Wklo)^T  (drop lo*lo)
#pragma unroll
        for (int ks = 0; ks < 4; ++ks) {
            const short8 ah = lds_load8(&ZH[rk_idx(16 * w + l15, ks * 32 + quad * 8)]);
            const short8 al = lds_load8(&ZL[rk_idx(16 * w + l15, ks * 32 + quad * 8)]);
#pragma unroll
            for (int jt = 0; jt < 4; ++jt) {
                const short8 bh_ = lds_load8(&KH[rk_idx(16 * jt + l15, ks * 32 + quad * 8)]);
                const short8 bl_ = lds_load8(&KL[rk_idx(16 * jt + l15, ks * 32 + quad * 8)]);
                lacc[jt] = MFMA(ah, bh_, lacc[jt]);
                lacc[jt] = MFMA(ah, bl_, lacc[jt]);
                lacc[jt] = MFMA(al, bh_, lacc[jt]);
            }
        }
    }

    // bias + scale + softmax. Row d = 16w+quad*4+r; col e = 16jt+l15.
    float ukv[4], bkv[4];
#pragma unroll
    for (int jt = 0; jt < 4; ++jt) {
        const int he = h * 64 + 16 * jt + l15;
        ukv[jt] = uk[b * E_ + he];
        bkv[jt] = bkF[he];
    }
    float L[4][4];
#pragma unroll
    for (int r = 0; r < 4; ++r) {
        const int hd = h * 64 + 16 * w + quad * 4 + r;
        const float uqr = uq[b * E_ + hd];
        const float bqr = bqF[hd];
#pragma unroll
        for (int jt = 0; jt < 4; ++jt)
            L[jt][r] = 0.125f * (lacc[jt][r] + bqr * ukv[jt] + bkv[jt] * uqr
                                 + 4096.f * bqr * bkv[jt]);
    }
#pragma unroll
    for (int r = 0; r < 4; ++r) {
        float m = fmaxf(fmaxf(L[0][r], L[1][r]), fmaxf(L[2][r], L[3][r]));
#pragma unroll
        for (int mask = 1; mask < 16; mask <<= 1) m = fmaxf(m, __shfl_xor(m, mask, 64));
        float s = 0.f;
#pragma unroll
        for (int jt = 0; jt < 4; ++jt) { L[jt][r] = __expf(L[jt][r] - m); s += L[jt][r]; }
#pragma unroll
        for (int mask = 1; mask < 16; mask <<= 1) s += __shfl_xor(s, mask, 64);
        const float inv = 1.f / s;
#pragma unroll
        for (int jt = 0; jt < 4; ++jt) L[jt][r] *= inv;
    }

    __syncthreads();   // all waves done with ZH region before PB overwrite
#pragma unroll
    for (int jt = 0; jt < 4; ++jt)
#pragma unroll
        for (int r = 0; r < 4; ++r)
            PB[(16 * w + quad * 4 + r) * 72 + 16 * jt + l15] = f2bf(L[jt][r]);
    __syncthreads();

    if (t < 64) {
        float s = 0.f;
        for (int e = 0; e < 64; ++e) s += bf2f(PB[t * 72 + e]) * bvF[h * 64 + e];
        bo[b * E_ + h * 64 + t] = s;
    }

    // Wo[hd, nc*64..] = sum_e P[d,e] Wv[he, nc*64..]
    unsigned short* Wob = Wo + (size_t)b * E_ * E_;
    for (int nc = 0; nc < 16; ++nc) {
        __syncthreads();
#pragma unroll
        for (int it = 0; it < 4; ++it) {     // WVT[n][e] transposed from Wv rows
            const int l = t + 256 * it;      // 0..1023
            const int n4 = l & 15, e = l >> 4;   // e 0..63
            float4 v = *(const float4*)(Wvh + (size_t)e * E_ + nc * 64 + n4 * 4);
            const float vv[4] = {v.x, v.y, v.z, v.w};
#pragma unroll
            for (int j = 0; j < 4; ++j) {
                const int n = n4 * 4 + j;
                WVT[n * 64 + swz(e >> 3, n) * 8 + (e & 7)] = f2bf(vv[j]);
            }
        }
        __syncthreads();
        floatx4 oacc[4] = {fz, fz, fz, fz};
#pragma unroll
        for (int ks = 0; ks < 2; ++ks) {
            const short8 a = lds_load8(&PB[(16 * w + l15) * 72 + ks * 32 + quad * 8]);
            const int q = ks * 4 + quad;
#pragma unroll
            for (int jt = 0; jt < 4; ++jt) {
                const int row = 16 * jt + l15;
                const short8 bb = lds_load8(&WVT[row * 64 + swz(q, row) * 8]);
                oacc[jt] = MFMA(a, bb, oacc[jt]);
            }
        }
#pragma unroll
        for (int jt = 0; jt < 4; ++jt)
#pragma unroll
            for (int r = 0; r < 4; ++r)
                Wob[(size_t)(h * 64 + 16 * w + quad * 4 + r) * E_ + nc * 64 + 16 * jt + l15]
                    = f2bf(oacc[jt][r]);
    }
}

// ---------------------------------------------------------------------------
// Out_b = X_b Wo_b^T + bo  (fp32 out). 128x128 tile, BK=32.
// Flat grid 2048, XCD (bid%8) == batch (Wo_b 2 MiB stays L2-resident).
// ---------------------------------------------------------------------------
__global__ __launch_bounds__(256) void out_gemm_kernel(
    const float* __restrict__ X, const unsigned short* __restrict__ Wo,
    const float* __restrict__ bo, float* __restrict__ Out)
{
    const int bid = blockIdx.x;
    const int b = bid & 7;
    const int rem = bid >> 3;            // 0..255
    const int n0 = (rem & 7) * 128;
    const int m0 = (rem >> 3) * 128;
    const int t = threadIdx.x, lane = t & 63, w = t >> 6;
    const int l15 = lane & 15, quad = lane >> 4;
    const int mw = 64 * (w >> 1), nw = 64 * (w & 1);

    __shared__ __align__(16) unsigned short As[128 * 32];
    __shared__ __align__(16) unsigned short Bs[128 * 32];

    const float* Xb = X + (size_t)b * S_ * E_;
    const unsigned short* Wb = Wo + (size_t)b * E_ * E_;
    const float* bob = bo + b * E_;
    float* Ob = Out + (size_t)b * S_ * E_;

    const floatx4 fz = {0.f, 0.f, 0.f, 0.f};
    floatx4 acc[4][4];
#pragma unroll
    for (int i = 0; i < 4; ++i)
#pragma unroll
        for (int j = 0; j < 4; ++j) acc[i][j] = fz;

    for (int k0 = 0; k0 < E_; k0 += 32) {
        __syncthreads();
#pragma unroll
        for (int it = 0; it < 4; ++it) {     // A: 128x32 fp32 -> bf16
            const int l = t + 256 * it;      // 0..1023
            const int c4 = l & 7, row = l >> 3;
            float4 v = *(const float4*)(Xb + (size_t)(m0 + row) * E_ + k0 + c4 * 4);
            ushort4 o = { f2bf(v.x), f2bf(v.y), f2bf(v.z), f2bf(v.w) };
            *(ushort4*)&As[row * 32 + SWIZ(row, c4 >> 1) * 8 + (c4 & 1) * 4] = o;
        }
#pragma unroll
        for (int it = 0; it < 2; ++it) {     // B: 128x32 bf16 (16B chunks)
            const int l = t + 256 * it;      // 0..511
            const int ch = l & 3, row = l >> 2;
            uint4 v = *(const uint4*)(Wb + (size_t)(n0 + row) * E_ + k0 + ch * 8);
            *(uint4*)&Bs[row * 32 + SWIZ(row, ch) * 8] = v;
        }
        __syncthreads();
        short8 af[4], bfr[4];
#pragma unroll
        for (int i = 0; i < 4; ++i) {
            const int row = mw + 16 * i + l15;
            af[i] = lds_load8(&As[row * 32 + SWIZ(row, quad) * 8]);
        }
#pragma unroll
        for (int j = 0; j < 4; ++j) {
            const int row = nw + 16 * j + l15;
            bfr[j] = lds_load8(&Bs[row * 32 + SWIZ(row, quad) * 8]);
        }
#pragma unroll
        for (int i = 0; i < 4; ++i)
#pragma unroll
            for (int j = 0; j < 4; ++j)
                acc[i][j] = MFMA(af[i], bfr[j], acc[i][j]);
    }

#pragma unroll
    for (int jt = 0; jt < 4; ++jt) {
        const int n = n0 + nw + 16 * jt + l15;
        const float bv_ = bob[n];
        float* colp = Ob + n;
#pragma unroll
        for (int i = 0; i < 4; ++i)
#pragma unroll
            for (int r = 0; r < 4; ++r) {
                const int m = m0 + mw + 16 * i + quad * 4 + r;
                colp[(size_t)m * E_] = acc[i][jt][r] + bv_;
            }
    }
}

// ---------------------------------------------------------------------------
extern "C" void kernel_launch(void* const* d_in, const int* in_sizes, int n_in,
                              void* d_out, int out_size, void* d_ws, size_t ws_size,
                              hipStream_t stream) {
    (void)in_sizes; (void)n_in; (void)out_size; (void)ws_size;
    const float* x  = (const float*)d_in[0];
    const float* Wq = (const float*)d_in[1];
    const float* bq = (const float*)d_in[2];
    const float* Wk = (const float*)d_in[3];
    const float* bk = (const float*)d_in[4];
    const float* Wv = (const float*)d_in[5];
    const float* bv = (const float*)d_in[6];

    // ws: Wo bf16 (16 MiB) | cpart,d2part (1 MiB) | c,gdiag,uq,uk,bo (160 KiB)
    unsigned short* Wo = (unsigned short*)d_ws;
    float* cpart  = (float*)(Wo + (size_t)B_ * E_ * E_);
    float* d2part = cpart  + 16 * B_ * E_;
    float* c      = d2part + 16 * B_ * E_;
    float* gdiag  = c      + B_ * E_;
    float* uq     = gdiag  + B_ * E_;
    float* uk     = uq     + B_ * E_;
    float* bo     = uk     + B_ * E_;

    // Scratch inside d_out (128 MiB): 4 gram partial slots of 32 MiB fill it.
    // greduce sums into slot 0 (=G); Z then reuses slot 1's region.
    // out_gemm overwrites the whole buffer last.
    float* Gp = (float*)d_out;
    float* G  = Gp;                                   // slot 0 after reduce
    float* Z  = Gp + (size_t)B_ * E_ * E_;            // slot 1 region

    sums_kernel<<<dim3(4, 8, 16), 256, 0, stream>>>(x, cpart, d2part);
    reduce_kernel<<<dim3(32), 256, 0, stream>>>(cpart, d2part, c, gdiag);
    uqk_kernel<<<dim3(4, 8), 256, 0, stream>>>(Wq, Wk, c, uq, uk);
    gram_kernel<<<dim3(1152), 256, 0, stream>>>(x, Gp);
    greduce_kernel<<<dim3(8192), 256, 0, stream>>>(Gp);
    z_kernel<<<dim3(512), 256, 0, stream>>>(G, Wq, gdiag, Z);
    attn_kernel<<<dim3(128), 256, 0, stream>>>(Z, bq, Wk, bk, Wv, bv,
                                               uq, uk, Wo, bo);
    out_gemm_kernel<<<dim3(2048), 256, 0, stream>>>(x, Wo, bo, (float*)d_out);
}